// Round 1
// baseline (627.075 us; speedup 1.0000x reference)
//
#include <hip/hip_runtime.h>

#define P_COLS 1024
#define NC 5

// Kernel 1: one streaming pass over X computing raw power sums s1..s5 per column.
// Thread t in each block owns columns [4t, 4t+4) via float4 loads; each block
// handles a contiguous slab of rows. Partials merged into d_ws via atomicAdd.
__global__ __launch_bounds__(256) void moments_kernel(
    const float* __restrict__ X, float* __restrict__ sums,
    int N, int rows_per_block)
{
    const int t = threadIdx.x;                       // 0..255 -> column group
    const int r0 = blockIdx.x * rows_per_block;
    int r1 = r0 + rows_per_block;
    if (r1 > N) r1 = N;

    float s1[4] = {0, 0, 0, 0};
    float s2[4] = {0, 0, 0, 0};
    float s3[4] = {0, 0, 0, 0};
    float s4[4] = {0, 0, 0, 0};
    float s5[4] = {0, 0, 0, 0};

    const float4* __restrict__ Xv = (const float4*)X;
    for (int r = r0; r < r1; ++r) {
        float4 x = Xv[(size_t)r * (P_COLS / 4) + t];
        float v[4] = {x.x, x.y, x.z, x.w};
#pragma unroll
        for (int c = 0; c < 4; ++c) {
            float a = v[c];
            float a2 = a * a;
            float a4 = a2 * a2;
            s1[c] += a;
            s2[c] += a2;
            s3[c] += a2 * a;   // fma
            s4[c] += a4;
            s5[c] += a4 * a;   // fma
        }
    }

#pragma unroll
    for (int c = 0; c < 4; ++c) {
        int col = 4 * t + c;
        atomicAdd(&sums[0 * P_COLS + col], s1[c]);
        atomicAdd(&sums[1 * P_COLS + col], s2[c]);
        atomicAdd(&sums[2 * P_COLS + col], s3[c]);
        atomicAdd(&sums[3 * P_COLS + col], s4[c]);
        atomicAdd(&sums[4 * P_COLS + col], s5[c]);
    }
}

// Kernel 2: raw sums -> central moments -> cumulants (fp64, tiny), subtract mu,
// project through W (5120x8), block-reduce to 8 outputs. One block, 1024 threads
// (thread j = column j).
__global__ __launch_bounds__(1024) void finalize_kernel(
    const float* __restrict__ sums, const float* __restrict__ mu_in,
    const float* __restrict__ W, float* __restrict__ out, int N)
{
    const int j = threadIdx.x;   // column
    const double inv = 1.0 / (double)N;

    double m  = (double)sums[0 * P_COLS + j] * inv;
    double M2 = (double)sums[1 * P_COLS + j] * inv;
    double M3 = (double)sums[2 * P_COLS + j] * inv;
    double M4 = (double)sums[3 * P_COLS + j] * inv;
    double M5 = (double)sums[4 * P_COLS + j] * inv;

    double mu2 = M2 - m * m;
    double mu3 = M3 - 3.0 * m * M2 + 2.0 * m * m * m;
    double mu5 = M5 - 5.0 * m * M4 + 10.0 * m * m * M3
               - 10.0 * m * m * m * M2 + 4.0 * m * m * m * m * m;

    float c[5];
    c[0] = (float)m;
    c[1] = 0.0f;                                  // mean(centered) == 0 analytically
    c[2] = (float)mu2;
    c[3] = (float)(mu3 - 3.0 * mu2 * mu2);        // torch: mu3 - 3*mu2^2
    c[4] = (float)(mu5 - 10.0 * mu2 * mu3);       // torch: mu5 - 10*mu2*mu3

    float acc[8] = {0, 0, 0, 0, 0, 0, 0, 0};
#pragma unroll
    for (int k = 0; k < NC; ++k) {
        float d = c[k] - mu_in[j * NC + k];
        const float* wrow = &W[(size_t)(j * NC + k) * 8];
#pragma unroll
        for (int o = 0; o < 8; ++o) acc[o] += d * wrow[o];
    }

    // wave (64-lane) shuffle reduction
#pragma unroll
    for (int off = 32; off >= 1; off >>= 1) {
#pragma unroll
        for (int o = 0; o < 8; ++o)
            acc[o] += __shfl_down(acc[o], off, 64);
    }

    __shared__ float red[16][8];
    const int wave = j >> 6;
    const int lane = j & 63;
    if (lane == 0) {
#pragma unroll
        for (int o = 0; o < 8; ++o) red[wave][o] = acc[o];
    }
    __syncthreads();
    if (j < 8) {
        float s = 0.0f;
#pragma unroll
        for (int wv = 0; wv < 16; ++wv) s += red[wv][j];
        out[j] = s;
    }
}

extern "C" void kernel_launch(void* const* d_in, const int* in_sizes, int n_in,
                              void* d_out, int out_size, void* d_ws, size_t ws_size,
                              hipStream_t stream) {
    const float* X  = (const float*)d_in[0];
    const float* mu = (const float*)d_in[1];
    const float* W  = (const float*)d_in[2];
    float* out = (float*)d_out;

    const int N = in_sizes[0] / P_COLS;            // 100000
    float* sums = (float*)d_ws;                    // 5*1024 floats = 20 KB

    hipMemsetAsync(sums, 0, NC * P_COLS * sizeof(float), stream);

    const int NB = 1024;
    const int rows_per_block = (N + NB - 1) / NB;
    moments_kernel<<<NB, 256, 0, stream>>>(X, sums, N, rows_per_block);
    finalize_kernel<<<1, 1024, 0, stream>>>(sums, mu, W, out, N);
}

// Round 2
// 563.585 us; speedup vs baseline: 1.1127x; 1.1127x over previous
//
#include <hip/hip_runtime.h>

#define P_COLS 1024
#define NC 5
#define NPAIRS (NC * P_COLS)      // 5120
#define NB_MOM 2048               // stage-1 blocks
#define NCHUNKS 16                // stage-2 b-chunks
#define BPC (NB_MOM / NCHUNKS)    // 128 blocks per chunk

// Stage 1: one streaming pass over X computing raw power sums s1..s5 per column.
// Thread t owns columns [4t, 4t+4) via float4 loads; each block handles a
// contiguous slab of rows and writes its 5120 partial sums to its private
// slice of d_ws (no atomics, fully deterministic).
__global__ __launch_bounds__(256) void moments_kernel(
    const float* __restrict__ X, float* __restrict__ partial1,
    int N, int rows_per_block)
{
    const int t = threadIdx.x;                       // 0..255 -> column group
    const int r0 = blockIdx.x * rows_per_block;
    int r1 = r0 + rows_per_block;
    if (r1 > N) r1 = N;

    float s1[4] = {0, 0, 0, 0};
    float s2[4] = {0, 0, 0, 0};
    float s3[4] = {0, 0, 0, 0};
    float s4[4] = {0, 0, 0, 0};
    float s5[4] = {0, 0, 0, 0};

    const float4* __restrict__ Xv = (const float4*)X;
#pragma unroll 2
    for (int r = r0; r < r1; ++r) {
        float4 x = Xv[(size_t)r * (P_COLS / 4) + t];
        float v[4] = {x.x, x.y, x.z, x.w};
#pragma unroll
        for (int c = 0; c < 4; ++c) {
            float a = v[c];
            float a2 = a * a;
            float a4 = a2 * a2;
            s1[c] += a;
            s2[c] += a2;
            s3[c] += a2 * a;   // fma
            s4[c] += a4;
            s5[c] += a4 * a;   // fma
        }
    }

    // layout: partial1[block][moment][col]  (block-major, coalesced stage-2 reads)
    float* out = partial1 + (size_t)blockIdx.x * NPAIRS;
#pragma unroll
    for (int c = 0; c < 4; ++c) {
        const int col = 4 * t + c;
        out[0 * P_COLS + col] = s1[c];
        out[1 * P_COLS + col] = s2[c];
        out[2 * P_COLS + col] = s3[c];
        out[3 * P_COLS + col] = s4[c];
        out[4 * P_COLS + col] = s5[c];
    }
}

// Stage 2: reduce 2048 block-partials down to NCHUNKS partials per (moment,col).
// blockIdx.x in [0,20): pair group; blockIdx.y in [0,16): chunk of 128 blocks.
__global__ __launch_bounds__(256) void reduce_kernel(
    const float* __restrict__ partial1, float* __restrict__ partial2)
{
    const int pair = blockIdx.x * 256 + threadIdx.x;   // 0..5119
    const int chunk = blockIdx.y;                      // 0..15
    const int b0 = chunk * BPC;
    float s = 0.0f;
#pragma unroll 4
    for (int b = 0; b < BPC; ++b)
        s += partial1[(size_t)(b0 + b) * NPAIRS + pair];
    partial2[(size_t)chunk * NPAIRS + pair] = s;
}

// Stage 3: fold last 16 partials (fp64), raw sums -> central moments ->
// cumulants, subtract mu, project through W (5120x8), block-reduce to 8 outs.
// One block, 1024 threads (thread j = column j).
__global__ __launch_bounds__(1024) void finalize_kernel(
    const float* __restrict__ partial2, const float* __restrict__ mu_in,
    const float* __restrict__ W, float* __restrict__ out, int N)
{
    const int j = threadIdx.x;   // column
    const double inv = 1.0 / (double)N;

    double M[5];
#pragma unroll
    for (int k = 0; k < NC; ++k) {
        double s = 0.0;
#pragma unroll
        for (int i = 0; i < NCHUNKS; ++i)
            s += (double)partial2[(size_t)i * NPAIRS + k * P_COLS + j];
        M[k] = s * inv;
    }

    const double m = M[0];
    const double mu2 = M[1] - m * m;
    const double mu3 = M[2] - 3.0 * m * M[1] + 2.0 * m * m * m;
    const double mu5 = M[4] - 5.0 * m * M[3] + 10.0 * m * m * M[2]
                     - 10.0 * m * m * m * M[1] + 4.0 * m * m * m * m * m;

    float c[5];
    c[0] = (float)m;
    c[1] = 0.0f;                                  // mean(centered) == 0 analytically
    c[2] = (float)mu2;
    c[3] = (float)(mu3 - 3.0 * mu2 * mu2);        // torch: mu3 - 3*mu2^2
    c[4] = (float)(mu5 - 10.0 * mu2 * mu3);       // torch: mu5 - 10*mu2*mu3

    float acc[8] = {0, 0, 0, 0, 0, 0, 0, 0};
#pragma unroll
    for (int k = 0; k < NC; ++k) {
        float d = c[k] - mu_in[j * NC + k];
        const float* wrow = &W[(size_t)(j * NC + k) * 8];
#pragma unroll
        for (int o = 0; o < 8; ++o) acc[o] += d * wrow[o];
    }

    // wave (64-lane) shuffle reduction
#pragma unroll
    for (int off = 32; off >= 1; off >>= 1) {
#pragma unroll
        for (int o = 0; o < 8; ++o)
            acc[o] += __shfl_down(acc[o], off, 64);
    }

    __shared__ float red[16][8];
    const int wave = j >> 6;
    const int lane = j & 63;
    if (lane == 0) {
#pragma unroll
        for (int o = 0; o < 8; ++o) red[wave][o] = acc[o];
    }
    __syncthreads();
    if (j < 8) {
        float s = 0.0f;
#pragma unroll
        for (int wv = 0; wv < 16; ++wv) s += red[wv][j];
        out[j] = s;
    }
}

extern "C" void kernel_launch(void* const* d_in, const int* in_sizes, int n_in,
                              void* d_out, int out_size, void* d_ws, size_t ws_size,
                              hipStream_t stream) {
    const float* X  = (const float*)d_in[0];
    const float* mu = (const float*)d_in[1];
    const float* W  = (const float*)d_in[2];
    float* out = (float*)d_out;

    const int N = in_sizes[0] / P_COLS;            // 100000

    float* partial1 = (float*)d_ws;                               // 2048*5120 f32 = 42 MB
    float* partial2 = partial1 + (size_t)NB_MOM * NPAIRS;         // 16*5120 f32 = 320 KB

    const int rows_per_block = (N + NB_MOM - 1) / NB_MOM;         // 49
    moments_kernel<<<NB_MOM, 256, 0, stream>>>(X, partial1, N, rows_per_block);

    dim3 rgrid(NPAIRS / 256, NCHUNKS);                            // (20, 16)
    reduce_kernel<<<rgrid, 256, 0, stream>>>(partial1, partial2);

    finalize_kernel<<<1, 1024, 0, stream>>>(partial2, mu, W, out, N);
}

// Round 4
// 531.443 us; speedup vs baseline: 1.1799x; 1.0605x over previous
//
#include <hip/hip_runtime.h>

#define P_COLS 1024
#define NC 5
#define NPAIRS (NC * P_COLS)      // 5120
#define NB_MOM 2048               // stage-1 blocks
#define NCHUNKS 16                // stage-2 b-chunks
#define BPC (NB_MOM / NCHUNKS)    // 128 blocks per chunk

typedef float f32x4 __attribute__((ext_vector_type(4)));

// Stage 1: one streaming pass over X computing raw power sums s1..s5 per column.
// Thread t owns columns [4t, 4t+4) via nontemporal float4 loads; each block
// handles a contiguous slab of rows and writes its 5120 partial sums (as five
// float4 stores) to its private slice of d_ws. No atomics, deterministic.
__global__ __launch_bounds__(256) void moments_kernel(
    const float* __restrict__ X, float* __restrict__ partial1,
    int N, int rows_per_block)
{
    const int t = threadIdx.x;                       // 0..255 -> column group
    const int r0 = blockIdx.x * rows_per_block;
    int r1 = r0 + rows_per_block;
    if (r1 > N) r1 = N;

    float s1[4] = {0, 0, 0, 0};
    float s2[4] = {0, 0, 0, 0};
    float s3[4] = {0, 0, 0, 0};
    float s4[4] = {0, 0, 0, 0};
    float s5[4] = {0, 0, 0, 0};

    const f32x4* __restrict__ Xv = (const f32x4*)X;
    int r = r0;
    // 4-row software pipeline: issue 4 independent nontemporal loads, then compute.
    for (; r + 4 <= r1; r += 4) {
        f32x4 xs[4];
        xs[0] = __builtin_nontemporal_load(&Xv[(size_t)(r + 0) * (P_COLS / 4) + t]);
        xs[1] = __builtin_nontemporal_load(&Xv[(size_t)(r + 1) * (P_COLS / 4) + t]);
        xs[2] = __builtin_nontemporal_load(&Xv[(size_t)(r + 2) * (P_COLS / 4) + t]);
        xs[3] = __builtin_nontemporal_load(&Xv[(size_t)(r + 3) * (P_COLS / 4) + t]);
#pragma unroll
        for (int q = 0; q < 4; ++q) {
#pragma unroll
            for (int c = 0; c < 4; ++c) {
                float a = xs[q][c];
                float a2 = a * a;
                float a4 = a2 * a2;
                s1[c] += a;
                s2[c] += a2;
                s3[c] += a2 * a;   // fma
                s4[c] += a4;
                s5[c] += a4 * a;   // fma
            }
        }
    }
    for (; r < r1; ++r) {
        f32x4 x = __builtin_nontemporal_load(&Xv[(size_t)r * (P_COLS / 4) + t]);
#pragma unroll
        for (int c = 0; c < 4; ++c) {
            float a = x[c];
            float a2 = a * a;
            float a4 = a2 * a2;
            s1[c] += a;
            s2[c] += a2;
            s3[c] += a2 * a;
            s4[c] += a4;
            s5[c] += a4 * a;
        }
    }

    // layout: partial1[block][moment][col] — five float4 stores
    f32x4* out4 = (f32x4*)(partial1 + (size_t)blockIdx.x * NPAIRS);
    f32x4 o;
    o[0] = s1[0]; o[1] = s1[1]; o[2] = s1[2]; o[3] = s1[3];
    out4[0 * (P_COLS / 4) + t] = o;
    o[0] = s2[0]; o[1] = s2[1]; o[2] = s2[2]; o[3] = s2[3];
    out4[1 * (P_COLS / 4) + t] = o;
    o[0] = s3[0]; o[1] = s3[1]; o[2] = s3[2]; o[3] = s3[3];
    out4[2 * (P_COLS / 4) + t] = o;
    o[0] = s4[0]; o[1] = s4[1]; o[2] = s4[2]; o[3] = s4[3];
    out4[3 * (P_COLS / 4) + t] = o;
    o[0] = s5[0]; o[1] = s5[1]; o[2] = s5[2]; o[3] = s5[3];
    out4[4 * (P_COLS / 4) + t] = o;
}

// Stage 2: reduce 2048 block-partials down to NCHUNKS partials per (moment,col).
// blockIdx.x in [0,20): pair group; blockIdx.y in [0,16): chunk of 128 blocks.
__global__ __launch_bounds__(256) void reduce_kernel(
    const float* __restrict__ partial1, float* __restrict__ partial2)
{
    const int pair = blockIdx.x * 256 + threadIdx.x;   // 0..5119
    const int chunk = blockIdx.y;                      // 0..15
    const int b0 = chunk * BPC;
    float s = 0.0f;
#pragma unroll 8
    for (int b = 0; b < BPC; ++b)
        s += __builtin_nontemporal_load(&partial1[(size_t)(b0 + b) * NPAIRS + pair]);
    partial2[(size_t)chunk * NPAIRS + pair] = s;
}

// Stage 3: fold last 16 partials (fp64), raw sums -> central moments ->
// cumulants, subtract mu, project through W (5120x8), block-reduce to 8 outs.
// One block, 1024 threads (thread j = column j).
__global__ __launch_bounds__(1024) void finalize_kernel(
    const float* __restrict__ partial2, const float* __restrict__ mu_in,
    const float* __restrict__ W, float* __restrict__ out, int N)
{
    const int j = threadIdx.x;   // column
    const double inv = 1.0 / (double)N;

    double M[5];
#pragma unroll
    for (int k = 0; k < NC; ++k) {
        double s = 0.0;
#pragma unroll
        for (int i = 0; i < NCHUNKS; ++i)
            s += (double)partial2[(size_t)i * NPAIRS + k * P_COLS + j];
        M[k] = s * inv;
    }

    const double m = M[0];
    const double mu2 = M[1] - m * m;
    const double mu3 = M[2] - 3.0 * m * M[1] + 2.0 * m * m * m;
    const double mu5 = M[4] - 5.0 * m * M[3] + 10.0 * m * m * M[2]
                     - 10.0 * m * m * m * M[1] + 4.0 * m * m * m * m * m;

    float c[5];
    c[0] = (float)m;
    c[1] = 0.0f;                                  // mean(centered) == 0 analytically
    c[2] = (float)mu2;
    c[3] = (float)(mu3 - 3.0 * mu2 * mu2);        // torch: mu3 - 3*mu2^2
    c[4] = (float)(mu5 - 10.0 * mu2 * mu3);       // torch: mu5 - 10*mu2*mu3

    float acc[8] = {0, 0, 0, 0, 0, 0, 0, 0};
#pragma unroll
    for (int k = 0; k < NC; ++k) {
        float d = c[k] - mu_in[j * NC + k];
        const float* wrow = &W[(size_t)(j * NC + k) * 8];
#pragma unroll
        for (int o = 0; o < 8; ++o) acc[o] += d * wrow[o];
    }

    // wave (64-lane) shuffle reduction
#pragma unroll
    for (int off = 32; off >= 1; off >>= 1) {
#pragma unroll
        for (int o = 0; o < 8; ++o)
            acc[o] += __shfl_down(acc[o], off, 64);
    }

    __shared__ float red[16][8];
    const int wave = j >> 6;
    const int lane = j & 63;
    if (lane == 0) {
#pragma unroll
        for (int o = 0; o < 8; ++o) red[wave][o] = acc[o];
    }
    __syncthreads();
    if (j < 8) {
        float s = 0.0f;
#pragma unroll
        for (int wv = 0; wv < 16; ++wv) s += red[wv][j];
        out[j] = s;
    }
}

extern "C" void kernel_launch(void* const* d_in, const int* in_sizes, int n_in,
                              void* d_out, int out_size, void* d_ws, size_t ws_size,
                              hipStream_t stream) {
    const float* X  = (const float*)d_in[0];
    const float* mu = (const float*)d_in[1];
    const float* W  = (const float*)d_in[2];
    float* out = (float*)d_out;

    const int N = in_sizes[0] / P_COLS;            // 100000

    float* partial1 = (float*)d_ws;                               // 2048*5120 f32 = 42 MB
    float* partial2 = partial1 + (size_t)NB_MOM * NPAIRS;         // 16*5120 f32 = 320 KB

    // No memset needed: stage 1 overwrites partial1, stage 2 overwrites partial2.
    const int rows_per_block = (N + NB_MOM - 1) / NB_MOM;         // 49
    moments_kernel<<<NB_MOM, 256, 0, stream>>>(X, partial1, N, rows_per_block);

    dim3 rgrid(NPAIRS / 256, NCHUNKS);                            // (20, 16)
    reduce_kernel<<<rgrid, 256, 0, stream>>>(partial1, partial2);

    finalize_kernel<<<1, 1024, 0, stream>>>(partial2, mu, W, out, N);
}

// Round 5
// 516.522 us; speedup vs baseline: 1.2140x; 1.0289x over previous
//
#include <hip/hip_runtime.h>

#define P_COLS 1024
#define NC 5
#define NPAIRS (NC * P_COLS)      // 5120
#define NB_MOM 1024               // stage-1 blocks (4 blocks/CU; 8-deep pipeline covers latency)
#define NCHUNKS 16                // stage-2 b-chunks
#define BPC (NB_MOM / NCHUNKS)    // 64 blocks per chunk

typedef float f32x4 __attribute__((ext_vector_type(4)));

// Stage 1: one streaming pass over X computing raw power sums s1..s5 per column.
// Thread t owns columns [4t, 4t+4) via nontemporal float4 loads; each block
// streams a contiguous ~98-row slab (392 KB sequential) and writes its 5120
// partial sums (five float4 stores) to its private slice of d_ws.
// No atomics, deterministic. 8-deep load pipeline: 8 outstanding 1 KiB
// wave-loads -> 128 KiB in flight per CU at 16 waves/CU, far above what is
// needed to saturate ~6.3 TB/s.
__global__ __launch_bounds__(256) void moments_kernel(
    const float* __restrict__ X, float* __restrict__ partial1,
    int N, int rows_per_block)
{
    const int t = threadIdx.x;                       // 0..255 -> column group
    const int r0 = blockIdx.x * rows_per_block;
    int r1 = r0 + rows_per_block;
    if (r1 > N) r1 = N;

    float s1[4] = {0, 0, 0, 0};
    float s2[4] = {0, 0, 0, 0};
    float s3[4] = {0, 0, 0, 0};
    float s4[4] = {0, 0, 0, 0};
    float s5[4] = {0, 0, 0, 0};

    const f32x4* __restrict__ Xv = (const f32x4*)X;
    int r = r0;
    for (; r + 8 <= r1; r += 8) {
        f32x4 xs[8];
#pragma unroll
        for (int q = 0; q < 8; ++q)
            xs[q] = __builtin_nontemporal_load(&Xv[(size_t)(r + q) * (P_COLS / 4) + t]);
#pragma unroll
        for (int q = 0; q < 8; ++q) {
#pragma unroll
            for (int c = 0; c < 4; ++c) {
                float a = xs[q][c];
                float a2 = a * a;
                float a4 = a2 * a2;
                s1[c] += a;
                s2[c] += a2;
                s3[c] += a2 * a;   // fma
                s4[c] += a4;
                s5[c] += a4 * a;   // fma
            }
        }
    }
    for (; r < r1; ++r) {
        f32x4 x = __builtin_nontemporal_load(&Xv[(size_t)r * (P_COLS / 4) + t]);
#pragma unroll
        for (int c = 0; c < 4; ++c) {
            float a = x[c];
            float a2 = a * a;
            float a4 = a2 * a2;
            s1[c] += a;
            s2[c] += a2;
            s3[c] += a2 * a;
            s4[c] += a4;
            s5[c] += a4 * a;
        }
    }

    // layout: partial1[block][moment][col] — five float4 stores
    f32x4* out4 = (f32x4*)(partial1 + (size_t)blockIdx.x * NPAIRS);
    f32x4 o;
    o[0] = s1[0]; o[1] = s1[1]; o[2] = s1[2]; o[3] = s1[3];
    out4[0 * (P_COLS / 4) + t] = o;
    o[0] = s2[0]; o[1] = s2[1]; o[2] = s2[2]; o[3] = s2[3];
    out4[1 * (P_COLS / 4) + t] = o;
    o[0] = s3[0]; o[1] = s3[1]; o[2] = s3[2]; o[3] = s3[3];
    out4[2 * (P_COLS / 4) + t] = o;
    o[0] = s4[0]; o[1] = s4[1]; o[2] = s4[2]; o[3] = s4[3];
    out4[3 * (P_COLS / 4) + t] = o;
    o[0] = s5[0]; o[1] = s5[1]; o[2] = s5[2]; o[3] = s5[3];
    out4[4 * (P_COLS / 4) + t] = o;
}

// Stage 2: reduce 1024 block-partials down to NCHUNKS partials per (moment,col).
// blockIdx.x in [0,20): pair group; blockIdx.y in [0,16): chunk of 64 blocks.
__global__ __launch_bounds__(256) void reduce_kernel(
    const float* __restrict__ partial1, float* __restrict__ partial2)
{
    const int pair = blockIdx.x * 256 + threadIdx.x;   // 0..5119
    const int chunk = blockIdx.y;                      // 0..15
    const int b0 = chunk * BPC;
    float s = 0.0f;
#pragma unroll 8
    for (int b = 0; b < BPC; ++b)
        s += __builtin_nontemporal_load(&partial1[(size_t)(b0 + b) * NPAIRS + pair]);
    partial2[(size_t)chunk * NPAIRS + pair] = s;
}

// Stage 3: fold last 16 partials (fp64), raw sums -> central moments ->
// cumulants, subtract mu, project through W (5120x8), block-reduce to 8 outs.
// One block, 1024 threads (thread j = column j).
__global__ __launch_bounds__(1024) void finalize_kernel(
    const float* __restrict__ partial2, const float* __restrict__ mu_in,
    const float* __restrict__ W, float* __restrict__ out, int N)
{
    const int j = threadIdx.x;   // column
    const double inv = 1.0 / (double)N;

    double M[5];
#pragma unroll
    for (int k = 0; k < NC; ++k) {
        double s = 0.0;
#pragma unroll
        for (int i = 0; i < NCHUNKS; ++i)
            s += (double)partial2[(size_t)i * NPAIRS + k * P_COLS + j];
        M[k] = s * inv;
    }

    const double m = M[0];
    const double mu2 = M[1] - m * m;
    const double mu3 = M[2] - 3.0 * m * M[1] + 2.0 * m * m * m;
    const double mu5 = M[4] - 5.0 * m * M[3] + 10.0 * m * m * M[2]
                     - 10.0 * m * m * m * M[1] + 4.0 * m * m * m * m * m;

    float c[5];
    c[0] = (float)m;
    c[1] = 0.0f;                                  // mean(centered) == 0 analytically
    c[2] = (float)mu2;
    c[3] = (float)(mu3 - 3.0 * mu2 * mu2);        // torch: mu3 - 3*mu2^2
    c[4] = (float)(mu5 - 10.0 * mu2 * mu3);       // torch: mu5 - 10*mu2*mu3

    float acc[8] = {0, 0, 0, 0, 0, 0, 0, 0};
#pragma unroll
    for (int k = 0; k < NC; ++k) {
        float d = c[k] - mu_in[j * NC + k];
        const float* wrow = &W[(size_t)(j * NC + k) * 8];
#pragma unroll
        for (int o = 0; o < 8; ++o) acc[o] += d * wrow[o];
    }

    // wave (64-lane) shuffle reduction
#pragma unroll
    for (int off = 32; off >= 1; off >>= 1) {
#pragma unroll
        for (int o = 0; o < 8; ++o)
            acc[o] += __shfl_down(acc[o], off, 64);
    }

    __shared__ float red[16][8];
    const int wave = j >> 6;
    const int lane = j & 63;
    if (lane == 0) {
#pragma unroll
        for (int o = 0; o < 8; ++o) red[wave][o] = acc[o];
    }
    __syncthreads();
    if (j < 8) {
        float s = 0.0f;
#pragma unroll
        for (int wv = 0; wv < 16; ++wv) s += red[wv][j];
        out[j] = s;
    }
}

extern "C" void kernel_launch(void* const* d_in, const int* in_sizes, int n_in,
                              void* d_out, int out_size, void* d_ws, size_t ws_size,
                              hipStream_t stream) {
    const float* X  = (const float*)d_in[0];
    const float* mu = (const float*)d_in[1];
    const float* W  = (const float*)d_in[2];
    float* out = (float*)d_out;

    const int N = in_sizes[0] / P_COLS;            // 100000

    float* partial1 = (float*)d_ws;                               // 1024*5120 f32 = 21 MB
    float* partial2 = partial1 + (size_t)NB_MOM * NPAIRS;         // 16*5120 f32 = 320 KB

    // No memset needed: stage 1 overwrites partial1, stage 2 overwrites partial2.
    const int rows_per_block = (N + NB_MOM - 1) / NB_MOM;         // 98
    moments_kernel<<<NB_MOM, 256, 0, stream>>>(X, partial1, N, rows_per_block);

    dim3 rgrid(NPAIRS / 256, NCHUNKS);                            // (20, 16)
    reduce_kernel<<<rgrid, 256, 0, stream>>>(partial1, partial2);

    finalize_kernel<<<1, 1024, 0, stream>>>(partial2, mu, W, out, N);
}